// Round 10
// baseline (72.616 us; speedup 1.0000x reference)
//
#include <hip/hip_runtime.h>
#include <stdint.h>

#define NTOK 8192
#define NCOL 4096     // DIM == VOCAB
#define RANK 256
#define TPB  256      // tokens per block (4 waves x 64 tokens)
#define CPB  128      // cols per block (8 col-tiles of 16)

typedef __attribute__((ext_vector_type(8))) short bf16x8;
typedef __attribute__((ext_vector_type(4))) float f32x4;

__device__ __forceinline__ unsigned short f2bf(float f) {
    unsigned int u = __float_as_uint(f);
    u += 0x7fffu + ((u >> 16) & 1u);   // RNE
    return (unsigned short)(u >> 16);
}

// ---- combined pre-pass ----
// blocks [0, 1024): A fp32 [4096][256] -> bf16 row-major (Abf, 2 MiB)
// blocks [1024, 1536): B fp32 [256][4096] -> bf16 MFMA-fragment order
//   frag layout: flat uint4 index = (ct*8 + ks)*64 + lane, 8 bf16 each:
//     element j = B[ks*32 + (lane>>4)*8 + j][ct*16 + (lane&15)]
//   used as the MFMA *A*-operand (swapped scheme): lane&15 = C-row = out col
__global__ __launch_bounds__(256) void prep_kernel(
    const float* __restrict__ A, const float* __restrict__ B,
    unsigned short* __restrict__ Abf, unsigned short* __restrict__ Bfrag)
{
    if (blockIdx.x < 1024) {
        int i = blockIdx.x * 256 + threadIdx.x;
        float4 v = reinterpret_cast<const float4*>(A)[i];
        ushort4 o;
        o.x = f2bf(v.x); o.y = f2bf(v.y); o.z = f2bf(v.z); o.w = f2bf(v.w);
        reinterpret_cast<ushort4*>(Abf)[i] = o;
    } else {
        int gt = (blockIdx.x - 1024) * 256 + threadIdx.x;
        int ct = gt >> 9;
        int rem = gt & 511;
        int ks = rem >> 6;
        int ln = rem & 63;
        int col = ct * 16 + (ln & 15);
        int kb  = ks * 32 + ((ln >> 4) << 3);
        unsigned short pk[8];
        #pragma unroll
        for (int j = 0; j < 8; ++j)
            pk[j] = f2bf(B[(size_t)(kb + j) * NCOL + col]);
        uint4 o;
        o.x = (unsigned)pk[0] | ((unsigned)pk[1] << 16);
        o.y = (unsigned)pk[2] | ((unsigned)pk[3] << 16);
        o.z = (unsigned)pk[4] | ((unsigned)pk[5] << 16);
        o.w = (unsigned)pk[6] | ((unsigned)pk[7] << 16);
        reinterpret_cast<uint4*>(Bfrag)[gt] = o;
    }
}

// ---- main: fused gather + LoRA GEMM + W add + mask ----
// M=64 tokens/wave (4 groups, confirmed traffic win) + swapped MFMA operands
// (C: lane = token, C-rows = 4 consecutive out cols -> float4 W-load/store).
// Grid (32,32)=1024 blocks, 16 waves/CU (r8's residency).
__global__ __launch_bounds__(256) void emb_lora_mfma(
    const int* __restrict__ x,
    const int* __restrict__ mask,
    const float* __restrict__ W,
    const unsigned short* __restrict__ Abf,
    const unsigned short* __restrict__ Bfrag,
    float* __restrict__ out)
{
    __shared__ int s_idx[TPB];
    __shared__ int s_msk[TPB];

    const int tid  = threadIdx.x;
    const int lane = tid & 63;
    const int wave = tid >> 6;        // wave owns tokens [wave*64, wave*64+64)
    const int tok0 = blockIdx.x * TPB;
    const int col0 = blockIdx.y * CPB;

    s_idx[tid] = x[tok0 + tid];
    s_msk[tid] = mask[tok0 + tid];
    __syncthreads();

    // A fragments (B-operand role): group g token = wave*64+g*16+(lane&15)
    bf16x8 af[4][8];
    int tokidx[4];
    unsigned mb = 0;
    #pragma unroll
    for (int g = 0; g < 4; ++g) {
        const int trow = wave * 64 + g * 16 + (lane & 15);
        tokidx[g] = s_idx[trow];
        mb |= (s_msk[trow] ? 1u : 0u) << g;
        const unsigned short* ap = Abf + (size_t)tokidx[g] * RANK + ((lane >> 4) << 3);
        #pragma unroll
        for (int s = 0; s < 8; ++s)
            af[g][s] = *reinterpret_cast<const bf16x8*>(ap + s * 32);
    }

    // epilogue offsets (float4 units): this lane's token per group, 4 cols
    const int colq = col0 + ((lane >> 4) << 2);
    unsigned wq[4], oq[4];
    #pragma unroll
    for (int g = 0; g < 4; ++g) {
        const int trow = wave * 64 + g * 16 + (lane & 15);
        wq[g] = ((unsigned)tokidx[g] * NCOL + colq) >> 2;
        oq[g] = ((unsigned)(tok0 + trow) * NCOL + colq) >> 2;
    }
    const float4* W4   = reinterpret_cast<const float4*>(W);
    float4*       out4 = reinterpret_cast<float4*>(out);

    // block's 8 col-tiles start at global col-tile blockIdx.y*8
    const uint4* bcol = reinterpret_cast<const uint4*>(Bfrag)
                        + (size_t)(blockIdx.y * 8) * 512 + lane;

    // W prefetch ring: 2 slots, 2-tile lead. Exec-masked `if` loads (NOT
    // ternary — r3 lesson: speculation doubled FETCH_SIZE).
    float4 wv[2][4];
    #pragma unroll
    for (int p = 0; p < 2; ++p) {
        #pragma unroll
        for (int g = 0; g < 4; ++g) {
            float4 v = {0.f, 0.f, 0.f, 0.f};
            if (!((mb >> g) & 1u)) v = W4[wq[g] + p * 4];
            wv[p][g] = v;
        }
    }

#define TILE_BODY(T, PF)                                                  \
    {                                                                     \
        uint4 bb[4];                                                      \
        _Pragma("unroll")                                                 \
        for (int s = 0; s < 4; ++s)                                       \
            bb[s] = bcol[(T) * 512 + s * 64];                             \
        float4 wc[4];                                                     \
        _Pragma("unroll")                                                 \
        for (int g = 0; g < 4; ++g) wc[g] = wv[(T) & 1][g];               \
        if (PF) {                                                         \
            _Pragma("unroll")                                             \
            for (int g = 0; g < 4; ++g) {                                 \
                float4 v = {0.f, 0.f, 0.f, 0.f};                          \
                if (!((mb >> g) & 1u)) v = W4[wq[g] + ((T) + 2) * 4];     \
                wv[(T) & 1][g] = v;                                       \
            }                                                             \
        }                                                                 \
        f32x4 acc[4];                                                     \
        _Pragma("unroll")                                                 \
        for (int g = 0; g < 4; ++g) acc[g] = (f32x4){0.f, 0.f, 0.f, 0.f}; \
        _Pragma("unroll")                                                 \
        for (int s = 0; s < 4; ++s) {                                     \
            bf16x8 b = __builtin_bit_cast(bf16x8, bb[s]);                 \
            _Pragma("unroll")                                             \
            for (int g = 0; g < 4; ++g)                                   \
                acc[g] = __builtin_amdgcn_mfma_f32_16x16x32_bf16(         \
                    b, af[g][s], acc[g], 0, 0, 0);                        \
        }                                                                 \
        _Pragma("unroll")                                                 \
        for (int s = 0; s < 4; ++s)                                       \
            bb[s] = bcol[(T) * 512 + (s + 4) * 64];                       \
        _Pragma("unroll")                                                 \
        for (int s = 0; s < 4; ++s) {                                     \
            bf16x8 b = __builtin_bit_cast(bf16x8, bb[s]);                 \
            _Pragma("unroll")                                             \
            for (int g = 0; g < 4; ++g)                                   \
                acc[g] = __builtin_amdgcn_mfma_f32_16x16x32_bf16(         \
                    b, af[g][s + 4], acc[g], 0, 0, 0);                    \
        }                                                                 \
        _Pragma("unroll")                                                 \
        for (int g = 0; g < 4; ++g) {                                     \
            float4 o = {0.f, 0.f, 0.f, 0.f};                              \
            if (!((mb >> g) & 1u)) {                                      \
                o.x = acc[g][0] + wc[g].x;                                \
                o.y = acc[g][1] + wc[g].y;                                \
                o.z = acc[g][2] + wc[g].z;                                \
                o.w = acc[g][3] + wc[g].w;                                \
            }                                                             \
            out4[oq[g] + (T) * 4] = o;                                    \
        }                                                                 \
    }

    TILE_BODY(0, 1); TILE_BODY(1, 1); TILE_BODY(2, 1);
    TILE_BODY(3, 1); TILE_BODY(4, 1); TILE_BODY(5, 1);
    // peeled tail: no prefetch (avoids OOB reads past the block's col range)
    TILE_BODY(6, 0); TILE_BODY(7, 0);
#undef TILE_BODY
}

extern "C" void kernel_launch(void* const* d_in, const int* in_sizes, int n_in,
                              void* d_out, int out_size, void* d_ws, size_t ws_size,
                              hipStream_t stream) {
    (void)in_sizes; (void)n_in; (void)out_size; (void)ws_size;

    const int*   x    = (const int*)d_in[0];
    const int*   mask = (const int*)d_in[1];
    const float* W    = (const float*)d_in[2];
    const float* A    = (const float*)d_in[3];
    const float* B    = (const float*)d_in[4];
    float*       out  = (float*)d_out;

    unsigned short* Abf   = (unsigned short*)d_ws;                       // 2 MiB
    unsigned short* Bfrag = (unsigned short*)((char*)d_ws + (2u << 20)); // 2 MiB

    prep_kernel<<<dim3(1536), dim3(256), 0, stream>>>(A, B, Abf, Bfrag);

    dim3 grid(NTOK / TPB, NCOL / CPB);   // (32, 32) = 1024 blocks
    emb_lora_mfma<<<grid, dim3(256), 0, stream>>>(x, mask, W, Abf, Bfrag, out);
}

// Round 11
// 54.255 us; speedup vs baseline: 1.3384x; 1.3384x over previous
//
#include <hip/hip_runtime.h>
#include <stdint.h>

#define NTOK 8192
#define NCOL 4096     // DIM == VOCAB
#define RANK 256
#define TPB  128      // tokens per block (4 waves x 32 tokens)
#define CPB  256      // cols per block

typedef __attribute__((ext_vector_type(8))) short bf16x8;
typedef __attribute__((ext_vector_type(4))) float f32x4;

__device__ __forceinline__ unsigned short f2bf(float f) {
    unsigned int u = __float_as_uint(f);
    u += 0x7fffu + ((u >> 16) & 1u);   // RNE
    return (unsigned short)(u >> 16);
}

// ---- combined pre-pass ----
// blocks [0, 1024): A fp32 [4096][256] -> bf16 row-major (Abf, 2 MiB, L2-resident)
// blocks [1024, 1536): B fp32 [256][4096] -> bf16 MFMA-B-fragment order
//   frag layout: flat uint4 index = (ct*8 + ks)*64 + lane, 8 bf16 each:
//     element j = B[ks*32 + (lane>>4)*8 + j][ct*16 + (lane&15)]
__global__ __launch_bounds__(256) void prep_kernel(
    const float* __restrict__ A, const float* __restrict__ B,
    unsigned short* __restrict__ Abf, unsigned short* __restrict__ Bfrag)
{
    if (blockIdx.x < 1024) {
        int i = blockIdx.x * 256 + threadIdx.x;
        float4 v = reinterpret_cast<const float4*>(A)[i];
        ushort4 o;
        o.x = f2bf(v.x); o.y = f2bf(v.y); o.z = f2bf(v.z); o.w = f2bf(v.w);
        reinterpret_cast<ushort4*>(Abf)[i] = o;
    } else {
        int gt = (blockIdx.x - 1024) * 256 + threadIdx.x;
        int ct = gt >> 9;
        int rem = gt & 511;
        int ks = rem >> 6;
        int ln = rem & 63;
        int col = ct * 16 + (ln & 15);
        int kb  = ks * 32 + ((ln >> 4) << 3);
        unsigned short pk[8];
        #pragma unroll
        for (int j = 0; j < 8; ++j)
            pk[j] = f2bf(B[(size_t)(kb + j) * NCOL + col]);
        uint4 o;
        o.x = (unsigned)pk[0] | ((unsigned)pk[1] << 16);
        o.y = (unsigned)pk[2] | ((unsigned)pk[3] << 16);
        o.z = (unsigned)pk[4] | ((unsigned)pk[5] << 16);
        o.w = (unsigned)pk[6] | ((unsigned)pk[7] << 16);
        reinterpret_cast<uint4*>(Bfrag)[gt] = o;
    }
}

// ---- main: fused gather + LoRA GEMM + W add + mask ----
// r8 structure (best known: 55.4 us): M=32 tok/wave, 2 token-groups share
// each B-fragment load. Single change vs r8: W prefetch ring depth 2 -> 4.
__global__ __launch_bounds__(256) void emb_lora_mfma(
    const int* __restrict__ x,
    const int* __restrict__ mask,
    const float* __restrict__ W,
    const unsigned short* __restrict__ Abf,
    const unsigned short* __restrict__ Bfrag,
    float* __restrict__ out)
{
    __shared__ int s_idx[TPB];
    __shared__ int s_msk[TPB];

    const int tid  = threadIdx.x;
    const int lane = tid & 63;
    const int wave = tid >> 6;        // wave owns tokens [wave*32, wave*32+32)
    const int tok0 = blockIdx.x * TPB;
    const int col0 = blockIdx.y * CPB;

    if (tid < TPB) {
        s_idx[tid] = x[tok0 + tid];
        s_msk[tid] = mask[tok0 + tid];
    }
    __syncthreads();

    // A fragments for both token groups (A-operand row = lane&15)
    const int a0row = s_idx[wave * 32 + (lane & 15)];
    const int a1row = s_idx[wave * 32 + 16 + (lane & 15)];
    const unsigned short* ap0 = Abf + (size_t)a0row * RANK + ((lane >> 4) << 3);
    const unsigned short* ap1 = Abf + (size_t)a1row * RANK + ((lane >> 4) << 3);
    bf16x8 aA[8], aB[8];
    #pragma unroll
    for (int s = 0; s < 8; ++s) {
        aA[s] = *reinterpret_cast<const bf16x8*>(ap0 + s * 32);
        aB[s] = *reinterpret_cast<const bf16x8*>(ap1 + s * 32);
    }

    // per-thread epilogue state: group g covers rows wave*32+g*16+(lane>>4)*4+r
    const int colb = col0 + (lane & 15);
    int msk0[4], msk1[4];
    unsigned woff0[4], woff1[4], ooff0[4], ooff1[4];
    #pragma unroll
    for (int r = 0; r < 4; ++r) {
        int row0 = wave * 32 + ((lane >> 4) << 2) + r;
        int row1 = row0 + 16;
        msk0[r] = s_msk[row0];
        msk1[r] = s_msk[row1];
        woff0[r] = (unsigned)s_idx[row0] * NCOL + colb;
        woff1[r] = (unsigned)s_idx[row1] * NCOL + colb;
        ooff0[r] = (unsigned)(tok0 + row0) * NCOL + colb;
        ooff1[r] = (unsigned)(tok0 + row1) * NCOL + colb;
    }

    // all 4 waves share these 16 col-tiles (B frags L1-resident after wave 0)
    const uint4* bcol = reinterpret_cast<const uint4*>(Bfrag)
                        + (size_t)(blockIdx.y * 16) * 512 + lane;

    // W prefetch rings, DEPTH 4 (r11 change; was 2), exec-masked loads
    // (explicit `if`, NOT ternary — r3: speculation doubled FETCH_SIZE)
    float wv0[4][4], wv1[4][4];
    #pragma unroll
    for (int p = 0; p < 4; ++p) {
        #pragma unroll
        for (int r = 0; r < 4; ++r) {
            float v0 = 0.0f, v1 = 0.0f;
            if (!msk0[r]) v0 = W[woff0[r] + p * 16];
            if (!msk1[r]) v1 = W[woff1[r] + p * 16];
            wv0[p][r] = v0;
            wv1[p][r] = v1;
        }
    }

#define TILE_BODY(T, SLOT, PF)                                           \
    {                                                                    \
        const int t_ = (T);                                              \
        uint4 bb[8];                                                     \
        _Pragma("unroll")                                                \
        for (int s = 0; s < 8; ++s)                                      \
            bb[s] = bcol[t_ * 512 + s * 64];                             \
        float wc0[4], wc1[4];                                            \
        _Pragma("unroll")                                                \
        for (int r = 0; r < 4; ++r) { wc0[r] = wv0[SLOT][r]; wc1[r] = wv1[SLOT][r]; } \
        if (PF) {                                                        \
            _Pragma("unroll")                                            \
            for (int r = 0; r < 4; ++r) {                                \
                float v0 = 0.0f, v1 = 0.0f;                              \
                if (!msk0[r]) v0 = W[woff0[r] + (t_ + 4) * 16];          \
                if (!msk1[r]) v1 = W[woff1[r] + (t_ + 4) * 16];          \
                wv0[SLOT][r] = v0;                                       \
                wv1[SLOT][r] = v1;                                       \
            }                                                            \
        }                                                                \
        f32x4 acc00 = {0.f,0.f,0.f,0.f}, acc01 = {0.f,0.f,0.f,0.f};      \
        f32x4 acc10 = {0.f,0.f,0.f,0.f}, acc11 = {0.f,0.f,0.f,0.f};      \
        _Pragma("unroll")                                                \
        for (int s = 0; s < 4; ++s) {                                    \
            bf16x8 b0 = __builtin_bit_cast(bf16x8, bb[s]);               \
            bf16x8 b1 = __builtin_bit_cast(bf16x8, bb[s + 4]);           \
            acc00 = __builtin_amdgcn_mfma_f32_16x16x32_bf16(aA[s],     b0, acc00, 0, 0, 0); \
            acc01 = __builtin_amdgcn_mfma_f32_16x16x32_bf16(aA[s + 4], b1, acc01, 0, 0, 0); \
            acc10 = __builtin_amdgcn_mfma_f32_16x16x32_bf16(aB[s],     b0, acc10, 0, 0, 0); \
            acc11 = __builtin_amdgcn_mfma_f32_16x16x32_bf16(aB[s + 4], b1, acc11, 0, 0, 0); \
        }                                                                \
        _Pragma("unroll")                                                \
        for (int r = 0; r < 4; ++r) {                                    \
            float v0 = msk0[r] ? 0.0f : (acc00[r] + acc01[r] + wc0[r]);  \
            float v1 = msk1[r] ? 0.0f : (acc10[r] + acc11[r] + wc1[r]);  \
            out[ooff0[r] + t_ * 16] = v0;                                \
            out[ooff1[r] + t_ * 16] = v1;                                \
        }                                                                \
    }

    #pragma unroll 1
    for (int t0 = 0; t0 < 12; t0 += 4) {
        TILE_BODY(t0 + 0, 0, 1);
        TILE_BODY(t0 + 1, 1, 1);
        TILE_BODY(t0 + 2, 2, 1);
        TILE_BODY(t0 + 3, 3, 1);
    }
    // peeled tail: no prefetch (avoids OOB reads past the block's col range)
    TILE_BODY(12, 0, 0);
    TILE_BODY(13, 1, 0);
    TILE_BODY(14, 2, 0);
    TILE_BODY(15, 3, 0);
#undef TILE_BODY
}

extern "C" void kernel_launch(void* const* d_in, const int* in_sizes, int n_in,
                              void* d_out, int out_size, void* d_ws, size_t ws_size,
                              hipStream_t stream) {
    (void)in_sizes; (void)n_in; (void)out_size; (void)ws_size;

    const int*   x    = (const int*)d_in[0];
    const int*   mask = (const int*)d_in[1];
    const float* W    = (const float*)d_in[2];
    const float* A    = (const float*)d_in[3];
    const float* B    = (const float*)d_in[4];
    float*       out  = (float*)d_out;

    unsigned short* Abf   = (unsigned short*)d_ws;                       // 2 MiB
    unsigned short* Bfrag = (unsigned short*)((char*)d_ws + (2u << 20)); // 2 MiB

    prep_kernel<<<dim3(1536), dim3(256), 0, stream>>>(A, B, Abf, Bfrag);

    dim3 grid(NTOK / TPB, NCOL / CPB);   // (64, 16) = 1024 blocks
    emb_lora_mfma<<<grid, dim3(256), 0, stream>>>(x, mask, W, Abf, Bfrag, out);
}

// Round 12
// 53.314 us; speedup vs baseline: 1.3621x; 1.0176x over previous
//
#include <hip/hip_runtime.h>
#include <stdint.h>

#define NTOK 8192
#define NCOL 4096     // DIM == VOCAB
#define RANK 256
#define TPB  128      // tokens per block (4 waves x 32 tokens)
#define CPB  256      // cols per block

typedef __attribute__((ext_vector_type(8))) short bf16x8;
typedef __attribute__((ext_vector_type(4))) float f32x4;

__device__ __forceinline__ unsigned short f2bf(float f) {
    unsigned int u = __float_as_uint(f);
    u += 0x7fffu + ((u >> 16) & 1u);   // RNE
    return (unsigned short)(u >> 16);
}

// ---- combined pre-pass ----
// blocks [0, 1024): A fp32 [4096][256] -> bf16 row-major (Abf, 2 MiB, L2-resident)
// blocks [1024, 1536): B fp32 [256][4096] -> bf16 MFMA-B-fragment order
//   frag layout: flat uint4 index = (ct*8 + ks)*64 + lane, 8 bf16 each:
//     element j = B[ks*32 + (lane>>4)*8 + j][ct*16 + (lane&15)]
__global__ __launch_bounds__(256) void prep_kernel(
    const float* __restrict__ A, const float* __restrict__ B,
    unsigned short* __restrict__ Abf, unsigned short* __restrict__ Bfrag)
{
    if (blockIdx.x < 1024) {
        int i = blockIdx.x * 256 + threadIdx.x;
        float4 v = reinterpret_cast<const float4*>(A)[i];
        ushort4 o;
        o.x = f2bf(v.x); o.y = f2bf(v.y); o.z = f2bf(v.z); o.w = f2bf(v.w);
        reinterpret_cast<ushort4*>(Abf)[i] = o;
    } else {
        int gt = (blockIdx.x - 1024) * 256 + threadIdx.x;
        int ct = gt >> 9;
        int rem = gt & 511;
        int ks = rem >> 6;
        int ln = rem & 63;
        int col = ct * 16 + (ln & 15);
        int kb  = ks * 32 + ((ln >> 4) << 3);
        unsigned short pk[8];
        #pragma unroll
        for (int j = 0; j < 8; ++j)
            pk[j] = f2bf(B[(size_t)(kb + j) * NCOL + col]);
        uint4 o;
        o.x = (unsigned)pk[0] | ((unsigned)pk[1] << 16);
        o.y = (unsigned)pk[2] | ((unsigned)pk[3] << 16);
        o.z = (unsigned)pk[4] | ((unsigned)pk[5] << 16);
        o.w = (unsigned)pk[6] | ((unsigned)pk[7] << 16);
        reinterpret_cast<uint4*>(Bfrag)[gt] = o;
    }
}

// ---- main: fused gather + LoRA GEMM + W add + mask ----
// r11 structure (best: 54.3 us) + ONE change: half-tile B software pipeline.
// bbL[4] persistently holds the lo-half of the current tile, loaded during
// the PREVIOUS tile's MFMA-hi phase -> every B-load batch is covered by
// ~8 MFMAs instead of stalling the chain at tile start.
__global__ __launch_bounds__(256) void emb_lora_mfma(
    const int* __restrict__ x,
    const int* __restrict__ mask,
    const float* __restrict__ W,
    const unsigned short* __restrict__ Abf,
    const unsigned short* __restrict__ Bfrag,
    float* __restrict__ out)
{
    __shared__ int s_idx[TPB];
    __shared__ int s_msk[TPB];

    const int tid  = threadIdx.x;
    const int lane = tid & 63;
    const int wave = tid >> 6;        // wave owns tokens [wave*32, wave*32+32)
    const int tok0 = blockIdx.x * TPB;
    const int col0 = blockIdx.y * CPB;

    if (tid < TPB) {
        s_idx[tid] = x[tok0 + tid];
        s_msk[tid] = mask[tok0 + tid];
    }
    __syncthreads();

    // A fragments for both token groups (A-operand row = lane&15)
    const int a0row = s_idx[wave * 32 + (lane & 15)];
    const int a1row = s_idx[wave * 32 + 16 + (lane & 15)];
    const unsigned short* ap0 = Abf + (size_t)a0row * RANK + ((lane >> 4) << 3);
    const unsigned short* ap1 = Abf + (size_t)a1row * RANK + ((lane >> 4) << 3);
    bf16x8 aA[8], aB[8];
    #pragma unroll
    for (int s = 0; s < 8; ++s) {
        aA[s] = *reinterpret_cast<const bf16x8*>(ap0 + s * 32);
        aB[s] = *reinterpret_cast<const bf16x8*>(ap1 + s * 32);
    }

    // per-thread epilogue state: group g covers rows wave*32+g*16+(lane>>4)*4+r
    const int colb = col0 + (lane & 15);
    int msk0[4], msk1[4];
    unsigned woff0[4], woff1[4], ooff0[4], ooff1[4];
    #pragma unroll
    for (int r = 0; r < 4; ++r) {
        int row0 = wave * 32 + ((lane >> 4) << 2) + r;
        int row1 = row0 + 16;
        msk0[r] = s_msk[row0];
        msk1[r] = s_msk[row1];
        woff0[r] = (unsigned)s_idx[row0] * NCOL + colb;
        woff1[r] = (unsigned)s_idx[row1] * NCOL + colb;
        ooff0[r] = (unsigned)(tok0 + row0) * NCOL + colb;
        ooff1[r] = (unsigned)(tok0 + row1) * NCOL + colb;
    }

    // all 4 waves share these 16 col-tiles (B frags L1-resident after wave 0)
    const uint4* bcol = reinterpret_cast<const uint4*>(Bfrag)
                        + (size_t)(blockIdx.y * 16) * 512 + lane;

    // W prefetch rings, depth 4 (r11 win), exec-masked loads
    // (explicit `if`, NOT ternary — r3: speculation doubled FETCH_SIZE)
    float wv0[4][4], wv1[4][4];
    #pragma unroll
    for (int p = 0; p < 4; ++p) {
        #pragma unroll
        for (int r = 0; r < 4; ++r) {
            float v0 = 0.0f, v1 = 0.0f;
            if (!msk0[r]) v0 = W[woff0[r] + p * 16];
            if (!msk1[r]) v1 = W[woff1[r] + p * 16];
            wv0[p][r] = v0;
            wv1[p][r] = v1;
        }
    }

    // B pipeline prologue: lo-half of tile 0
    uint4 bbL[4];
    #pragma unroll
    for (int s = 0; s < 4; ++s)
        bbL[s] = bcol[s * 64];

#define TILE_BODY(T, SLOT, PF)                                           \
    {                                                                    \
        const int t_ = (T);                                              \
        /* issue hi-half loads for this tile */                          \
        uint4 bbH[4];                                                    \
        _Pragma("unroll")                                                \
        for (int s = 0; s < 4; ++s)                                      \
            bbH[s] = bcol[t_ * 512 + (s + 4) * 64];                      \
        float wc0[4], wc1[4];                                            \
        _Pragma("unroll")                                                \
        for (int r = 0; r < 4; ++r) { wc0[r] = wv0[SLOT][r]; wc1[r] = wv1[SLOT][r]; } \
        if (PF) {                                                        \
            _Pragma("unroll")                                            \
            for (int r = 0; r < 4; ++r) {                                \
                float v0 = 0.0f, v1 = 0.0f;                              \
                if (!msk0[r]) v0 = W[woff0[r] + (t_ + 4) * 16];          \
                if (!msk1[r]) v1 = W[woff1[r] + (t_ + 4) * 16];          \
                wv0[SLOT][r] = v0;                                       \
                wv1[SLOT][r] = v1;                                       \
            }                                                            \
        }                                                                \
        /* MFMA on lo-half (bbL was loaded during the previous tile) */  \
        f32x4 acc00 = {0.f,0.f,0.f,0.f}, acc01 = {0.f,0.f,0.f,0.f};      \
        f32x4 acc10 = {0.f,0.f,0.f,0.f}, acc11 = {0.f,0.f,0.f,0.f};      \
        _Pragma("unroll")                                                \
        for (int s = 0; s < 4; ++s) {                                    \
            bf16x8 b0 = __builtin_bit_cast(bf16x8, bbL[s]);              \
            acc00 = __builtin_amdgcn_mfma_f32_16x16x32_bf16(aA[s], b0, acc00, 0, 0, 0); \
            acc10 = __builtin_amdgcn_mfma_f32_16x16x32_bf16(aB[s], b0, acc10, 0, 0, 0); \
        }                                                                \
        /* prefetch lo-half of the NEXT tile into bbL (tail: reload self) */ \
        {                                                                \
            const int tn_ = (t_ < 15) ? (t_ + 1) : t_;                   \
            _Pragma("unroll")                                            \
            for (int s = 0; s < 4; ++s)                                  \
                bbL[s] = bcol[tn_ * 512 + s * 64];                       \
        }                                                                \
        /* MFMA on hi-half (covered by MFMA-lo above) */                 \
        _Pragma("unroll")                                                \
        for (int s = 0; s < 4; ++s) {                                    \
            bf16x8 b1 = __builtin_bit_cast(bf16x8, bbH[s]);              \
            acc01 = __builtin_amdgcn_mfma_f32_16x16x32_bf16(aA[s + 4], b1, acc01, 0, 0, 0); \
            acc11 = __builtin_amdgcn_mfma_f32_16x16x32_bf16(aB[s + 4], b1, acc11, 0, 0, 0); \
        }                                                                \
        _Pragma("unroll")                                                \
        for (int r = 0; r < 4; ++r) {                                    \
            float v0 = msk0[r] ? 0.0f : (acc00[r] + acc01[r] + wc0[r]);  \
            float v1 = msk1[r] ? 0.0f : (acc10[r] + acc11[r] + wc1[r]);  \
            out[ooff0[r] + t_ * 16] = v0;                                \
            out[ooff1[r] + t_ * 16] = v1;                                \
        }                                                                \
    }

    #pragma unroll 1
    for (int t0 = 0; t0 < 12; t0 += 4) {
        TILE_BODY(t0 + 0, 0, 1);
        TILE_BODY(t0 + 1, 1, 1);
        TILE_BODY(t0 + 2, 2, 1);
        TILE_BODY(t0 + 3, 3, 1);
    }
    // peeled tail: no W prefetch (avoids OOB reads past the block's col range)
    TILE_BODY(12, 0, 0);
    TILE_BODY(13, 1, 0);
    TILE_BODY(14, 2, 0);
    TILE_BODY(15, 3, 0);
#undef TILE_BODY
}

extern "C" void kernel_launch(void* const* d_in, const int* in_sizes, int n_in,
                              void* d_out, int out_size, void* d_ws, size_t ws_size,
                              hipStream_t stream) {
    (void)in_sizes; (void)n_in; (void)out_size; (void)ws_size;

    const int*   x    = (const int*)d_in[0];
    const int*   mask = (const int*)d_in[1];
    const float* W    = (const float*)d_in[2];
    const float* A    = (const float*)d_in[3];
    const float* B    = (const float*)d_in[4];
    float*       out  = (float*)d_out;

    unsigned short* Abf   = (unsigned short*)d_ws;                       // 2 MiB
    unsigned short* Bfrag = (unsigned short*)((char*)d_ws + (2u << 20)); // 2 MiB

    prep_kernel<<<dim3(1536), dim3(256), 0, stream>>>(A, B, Abf, Bfrag);

    dim3 grid(NTOK / TPB, NCOL / CPB);   // (64, 16) = 1024 blocks
    emb_lora_mfma<<<grid, dim3(256), 0, stream>>>(x, mask, W, Abf, Bfrag, out);
}